// Round 12
// baseline (422.697 us; speedup 1.0000x reference)
//
#include <hip/hip_runtime.h>
#include <math.h>

static constexpr int B_  = 16;
static constexpr int C_  = 512;
static constexpr int L_  = 2048;

typedef __attribute__((ext_vector_type(8))) short bf16x8;
typedef __attribute__((ext_vector_type(4))) float f32x4;

__device__ __forceinline__ unsigned short f2bf(float f) {
    unsigned int u = __float_as_uint(f);
    unsigned int r = (u + 0x7FFFu + ((u >> 16) & 1u)) >> 16;   // RNE
    return (unsigned short)r;
}

// async global->LDS, 16 bytes per lane; LDS dest = uniform base + lane*16
__device__ __forceinline__ void async_copy16(const void* g, void* l) {
    __builtin_amdgcn_global_load_lds(
        (const __attribute__((address_space(1))) unsigned int*)g,
        (__attribute__((address_space(3))) unsigned int*)l, 16, 0, 0);
}

// ---------------------------------------------------------------------------
// MERGED cast kernel: grid (32, 8, 17).  z<16: x->xt transpose+cast;
// z==16: W cast (160 of 256 blocks).  (R11, verified)
// ---------------------------------------------------------------------------
__global__ __launch_bounds__(256)
void cast_xw_kernel(const float* __restrict__ x, unsigned short* __restrict__ xt,
                    const float* __restrict__ Wq, const float* __restrict__ Wk,
                    const float* __restrict__ Wv, unsigned short* __restrict__ Wb)
{
    const int t = threadIdx.x;
    if (blockIdx.z == 16) {
        const int bid = blockIdx.y * 32 + blockIdx.x;
        if (bid >= 160) return;
        const int idx = (bid * 256 + t) * 8;
        const int m = idx >> 9;
        const int c = idx & 511;
        const float* src = (m < 64) ? (Wq + (size_t)m * 512)
                         : (m < 128) ? (Wk + (size_t)(m - 64) * 512)
                                     : (Wv + (size_t)(m - 128) * 512);
        float4 a = *(const float4*)(src + c);
        float4 d = *(const float4*)(src + c + 4);
        union { unsigned short h[8]; uint4 v; } o;
        o.h[0]=f2bf(a.x); o.h[1]=f2bf(a.y); o.h[2]=f2bf(a.z); o.h[3]=f2bf(a.w);
        o.h[4]=f2bf(d.x); o.h[5]=f2bf(d.y); o.h[6]=f2bf(d.z); o.h[7]=f2bf(d.w);
        *(uint4*)(Wb + idx) = o.v;
        return;
    }

    __shared__ float T[64][65];
    const int l0 = blockIdx.x * 64;
    const int c0 = blockIdx.y * 64;
    const int b  = blockIdx.z;

    {
        const int cr = t >> 2;
        const int lq = (t & 3) * 4;
        const float* src = x + ((size_t)b * 512 + c0 + cr) * 2048 + l0 + lq;
        #pragma unroll
        for (int e = 0; e < 4; ++e) {
            float4 f = *(const float4*)(src + e * 16);
            const int lc = lq + e * 16;
            T[lc + 0][cr] = f.x;
            T[lc + 1][cr] = f.y;
            T[lc + 2][cr] = f.z;
            T[lc + 3][cr] = f.w;
        }
    }
    __syncthreads();
    {
        const int lr = t >> 2;
        const int cq = (t & 3) * 8;
        unsigned short* dst = xt + ((size_t)b * 2048 + l0 + lr) * 512 + c0;
        #pragma unroll
        for (int e = 0; e < 2; ++e) {
            union { unsigned short h[8]; uint4 v; } o;
            #pragma unroll
            for (int j = 0; j < 8; ++j) o.h[j] = f2bf(T[lr][cq + e*32 + j]);
            *(uint4*)(dst + cq + e*32) = o.v;
        }
    }
}

// ---------------------------------------------------------------------------
// Proj GEMM (MFMA, global_load_lds staging) — verified ~45us. XCD-chunked.
// ---------------------------------------------------------------------------
__global__ __launch_bounds__(256)
void proj_mfma_kernel(const unsigned short* __restrict__ xt,
                      const unsigned short* __restrict__ Wb,
                      const float* __restrict__ bq, const float* __restrict__ bk,
                      const float* __restrict__ bv,
                      unsigned short* __restrict__ qt, unsigned short* __restrict__ kt,
                      unsigned short* __restrict__ v)
{
    __shared__ unsigned short As[128 * 64];
    __shared__ unsigned short Bs[128 * 64];

    const int t     = threadIdx.x;
    const int bid   = blockIdx.x;
    const int xcd   = bid & 7;
    const int ii    = bid >> 3;
    const int nt5   = ii % 5;
    const int mloc  = ii / 5;
    const int mtile = xcd * 32 + mloc;
    const int row0  = mtile * 128;
    const int b     = mtile >> 4;
    const int l0    = (mtile & 15) * 128;
    const int c0t   = nt5 * 128;

    const int w    = t >> 6;
    const int lane = t & 63;
    const int quad = lane >> 4;
    const int n16  = lane & 15;
    const int mq   = (w & 1) * 64;
    const int nq   = (w >> 1) * 64;
    const int sr   = lane >> 3;
    const int sc   = (lane & 7) * 8;

    f32x4 acc[4][4];
    #pragma unroll
    for (int i = 0; i < 4; ++i)
        #pragma unroll
        for (int j = 0; j < 4; ++j) acc[i][j] = (f32x4){0.f,0.f,0.f,0.f};

    for (int kt_ = 0; kt_ < 512; kt_ += 64) {
        #pragma unroll
        for (int p = 0; p < 4; ++p) {
            const int rbase = w * 32 + p * 8;
            async_copy16(xt + ((size_t)(row0 + rbase + sr)) * 512 + kt_ + sc,
                         &As[rbase * 64]);
            async_copy16(Wb + ((size_t)(c0t + rbase + sr)) * 512 + kt_ + sc,
                         &Bs[rbase * 64]);
        }
        __syncthreads();

        #pragma unroll
        for (int ks = 0; ks < 2; ++ks) {
            bf16x8 a[4], bb[4];
            #pragma unroll
            for (int mt = 0; mt < 4; ++mt)
                a[mt] = *(const bf16x8*)&As[(mq + mt*16 + n16) * 64 + ks*32 + quad*8];
            #pragma unroll
            for (int nt = 0; nt < 4; ++nt)
                bb[nt] = *(const bf16x8*)&Bs[(nq + nt*16 + n16) * 64 + ks*32 + quad*8];
            #pragma unroll
            for (int mt = 0; mt < 4; ++mt)
                #pragma unroll
                for (int nt = 0; nt < 4; ++nt)
                    acc[mt][nt] = __builtin_amdgcn_mfma_f32_16x16x32_bf16(a[mt], bb[nt], acc[mt][nt], 0, 0, 0);
        }
        __syncthreads();
    }

    #pragma unroll
    for (int nt = 0; nt < 4; ++nt) {
        const int crow = c0t + nq + nt*16 + n16;
        const float bias = (crow < 64) ? bq[crow] : (crow < 128) ? bk[crow - 64] : bv[crow - 128];
        #pragma unroll
        for (int mt = 0; mt < 4; ++mt) {
            const int lb = l0 + mq + mt*16 + quad*4;
            if (crow < 64) {
                #pragma unroll
                for (int r = 0; r < 4; ++r)
                    qt[((size_t)b * 2048 + lb + r) * 64 + crow] = f2bf(acc[mt][nt][r] + bias);
            } else if (crow < 128) {
                #pragma unroll
                for (int r = 0; r < 4; ++r)
                    kt[((size_t)b * 2048 + lb + r) * 64 + crow - 64] = f2bf(acc[mt][nt][r] + bias);
            } else {
                ushort4 o;
                o.x = f2bf(acc[mt][nt][0] + bias);
                o.y = f2bf(acc[mt][nt][1] + bias);
                o.z = f2bf(acc[mt][nt][2] + bias);
                o.w = f2bf(acc[mt][nt][3] + bias);
                *(ushort4*)(v + ((size_t)b * 512 + crow - 128) * 2048 + lb) = o;
            }
        }
    }
}

// ---------------------------------------------------------------------------
// Attention v6 = R4 geometry + R5's K-double-buffer fix (the combo never
// tested). grid (64,16) = 1024 blocks x 256 thr (4 waves), 3 blocks/CU.
// Block = 64 q x 256 ch (half); wave = 64 q x 64 ch PRIVATE stripe.
//  - V global->REG, double-buffered, consumed one full iter after issue.
//    No V LDS, no DMA -> barrier is lgkmcnt-only (no vmcnt drain).
//  - K double-buffered in regs, loaded TWO tiles ahead, consumed one body
//    after issue (fixes R4's same-iter K load-use, its measured killer).
//  - QK duplicated across the 2 ch-half blocks (4 of 20 MFMAs).
//  - LDS: Ps[2][64][40] + l_sh = 10.5KB. launch_bounds (256,3) — R4-proven
//    (84 VGPR, no spill); +16 VGPR for K dbuf stays within the 3-wave cap.
// ---------------------------------------------------------------------------
__global__ __launch_bounds__(256, 3)
void attn_kernel(const unsigned short* __restrict__ qt,
                 const unsigned short* __restrict__ kt,
                 const unsigned short* __restrict__ vg,
                 const float* __restrict__ x,
                 const float* __restrict__ gamma,
                 float* __restrict__ out)
{
    // LDS: Ps[2][64][40] bf16 (10240B) | l_sh[64] f32; Osc overlaps Ps in epilogue
    __shared__ __align__(16) char smem[10496];
    unsigned short* Ps   = (unsigned short*)smem;        // [2][64*40]
    float*          l_sh = (float*)(smem + 10240);       // [64]
    float*          Osc  = (float*)smem;                 // epilogue only

    const int t    = threadIdx.x;
    // XCD-aware remap: XCD n%8 owns batches {2x,2x+1} (V working set 4MB -> L2)
    const int nlin = blockIdx.y * 64 + blockIdx.x;       // 0..1023
    const int k_   = nlin >> 3;                          // 0..127
    const int b    = ((nlin & 7) << 1) | (k_ & 1);
    const int r_   = k_ >> 1;                            // 0..63
    const int half = r_ & 1;                             // ch-half
    const int i0b  = (r_ >> 1) * 64;                     // q-tile
    const int w    = t >> 6;
    const int lane = t & 63;
    const int quad = lane >> 4;
    const int n16  = lane & 15;

    // Q fragments (A-layout: m = query = n16, k = ck)
    bf16x8 Qf[2];
    {
        const unsigned short* qp = qt + ((size_t)b * 2048 + i0b + w*16 + n16) * 64 + quad * 8;
        Qf[0] = *(const bf16x8*)(qp);
        Qf[1] = *(const bf16x8*)(qp + 32);
    }

    const unsigned short* kbase = kt + (size_t)b * 2048 * 64;
    // wave's private 64-channel stripe of V
    const unsigned short* vbase = vg + ((size_t)b * 512 + half * 256 + w * 64) * 2048;

    float l_part[4] = {0.f, 0.f, 0.f, 0.f};
    f32x4 O[4][4];   // [ct][qb]: 64 ch x 64 q per wave
    #pragma unroll
    for (int ct = 0; ct < 4; ++ct)
        #pragma unroll
        for (int qb = 0; qb < 4; ++qb) O[ct][qb] = (f32x4){0.f,0.f,0.f,0.f};

    bf16x8 Va[4], Vb[4];       // V reg double-buffer (per-wave private)
    bf16x8 Ka[2][2], Kb[2][2]; // K reg double-buffer (whole 32-j tile)

    // ---------------- prologue: QK(0)->Ps[0] (K0 inline); V(0)->Va; K(1)->Ka
    {
        bf16x8 K0[2][2];
        #pragma unroll
        for (int jb = 0; jb < 2; ++jb)
            #pragma unroll
            for (int h = 0; h < 2; ++h)
                K0[jb][h] = *(const bf16x8*)(kbase + (size_t)(jb*16 + n16) * 64 + h*32 + quad*8);
        #pragma unroll
        for (int ct = 0; ct < 4; ++ct)
            Va[ct] = *(const bf16x8*)(vbase + (size_t)(ct*16 + n16) * 2048 + quad*8);
        #pragma unroll
        for (int jb = 0; jb < 2; ++jb)
            #pragma unroll
            for (int h = 0; h < 2; ++h)
                Ka[jb][h] = *(const bf16x8*)(kbase + (size_t)(32 + jb*16 + n16) * 64 + h*32 + quad*8);

        f32x4 s[2];
        #pragma unroll
        for (int jb = 0; jb < 2; ++jb) {
            s[jb] = (f32x4){0.f,0.f,0.f,0.f};
            s[jb] = __builtin_amdgcn_mfma_f32_16x16x32_bf16(Qf[0], K0[jb][0], s[jb], 0, 0, 0);
            s[jb] = __builtin_amdgcn_mfma_f32_16x16x32_bf16(Qf[1], K0[jb][1], s[jb], 0, 0, 0);
        }
        #pragma unroll
        for (int jb = 0; jb < 2; ++jb)
            #pragma unroll
            for (int r = 0; r < 4; ++r) {
                const float pv = __expf(s[jb][r] - 80.0f);
                l_part[r] += pv;
                Ps[(w*16 + quad*4 + r) * 40 + jb*16 + n16] = f2bf(pv);
            }
    }
    asm volatile("s_waitcnt lgkmcnt(0)" ::: "memory");
    __builtin_amdgcn_s_barrier();   // Ps[0] visible

    // ---------------- main loop: 2x unrolled, V and K reg role swap ---------
    // body(IT): Pf<-Ps[CB]; issue V(IT+1)->VN and K(IT+2)->KN; PV(IT) w/ VC;
    //           QK(IT+1) w/ KC (loaded one body ago) -> Ps[CB^1]; barrier.
    // NO same-iteration load-use anywhere.
#define ATTN_BODY(IT, CB, VC, VN, KC, KN, LAST)                                \
    {                                                                          \
        bf16x8 Pf[4];                                                          \
        _Pragma("unroll")                                                      \
        for (int qb = 0; qb < 4; ++qb)                                         \
            Pf[qb] = *(const bf16x8*)&Ps[(CB)*2560 + (qb*16 + n16)*40 + quad*8]; \
        const int jv = (((IT) + 1) * 32) & 2047;   /* wraps: harmless reads */ \
        const int jk = (((IT) + 2) * 32) & 2047;                               \
        _Pragma("unroll")                                                      \
        for (int ct = 0; ct < 4; ++ct)                                         \
            VN[ct] = *(const bf16x8*)(vbase + (size_t)(ct*16 + n16) * 2048 + jv + quad*8); \
        asm volatile("" ::: "memory");  /* pin issue order: V then K */        \
        {                                                                      \
            const unsigned short* kp_ = kbase + (size_t)jk * 64;               \
            _Pragma("unroll")                                                  \
            for (int jb = 0; jb < 2; ++jb)                                     \
                _Pragma("unroll")                                              \
                for (int h = 0; h < 2; ++h)                                    \
                    KN[jb][h] = *(const bf16x8*)(kp_ + (size_t)(jb*16 + n16)*64 + h*32 + quad*8); \
        }                                                                      \
        asm volatile("" ::: "memory");  /* loads issued before compute */      \
        __builtin_amdgcn_s_setprio(1);                                         \
        _Pragma("unroll")                                                      \
        for (int ct = 0; ct < 4; ++ct) {                                       \
            _Pragma("unroll")                                                  \
            for (int qb = 0; qb < 4; ++qb)                                     \
                O[ct][qb] = __builtin_amdgcn_mfma_f32_16x16x32_bf16(VC[ct], Pf[qb], O[ct][qb], 0, 0, 0); \
        }                                                                      \
        __builtin_amdgcn_s_setprio(0);                                         \
        if (!(LAST)) {                                                         \
            f32x4 s_[2];                                                       \
            _Pragma("unroll")                                                  \
            for (int jb = 0; jb < 2; ++jb) {                                   \
                s_[jb] = (f32x4){0.f,0.f,0.f,0.f};                             \
                s_[jb] = __builtin_amdgcn_mfma_f32_16x16x32_bf16(Qf[0], KC[jb][0], s_[jb], 0, 0, 0); \
                s_[jb] = __builtin_amdgcn_mfma_f32_16x16x32_bf16(Qf[1], KC[jb][1], s_[jb], 0, 0, 0); \
            }                                                                  \
            _Pragma("unroll")                                                  \
            for (int jb = 0; jb < 2; ++jb)                                     \
                _Pragma("unroll")                                              \
                for (int r = 0; r < 4; ++r) {                                  \
                    const float pv = __expf(s_[jb][r] - 80.0f);                \
                    l_part[r] += pv;                                           \
                    Ps[((CB)^1)*2560 + (w*16 + quad*4 + r)*40 + jb*16 + n16] = f2bf(pv); \
                }                                                              \
        }                                                                      \
        asm volatile("s_waitcnt lgkmcnt(0)" ::: "memory");                     \
        __builtin_amdgcn_s_barrier();                                          \
    }

    for (int it = 0; it < 64; it += 2) {
        ATTN_BODY(it,     0, Va, Vb, Ka, Kb, false)
        ATTN_BODY((it+1), 1, Vb, Va, Kb, Ka, (it == 62))
    }
#undef ATTN_BODY

    // ---- reduce l across the 16 j-lanes (once), publish
    #pragma unroll
    for (int r = 0; r < 4; ++r) {
        float sm = l_part[r];
        sm += __shfl_xor(sm, 1);
        sm += __shfl_xor(sm, 2);
        sm += __shfl_xor(sm, 4);
        sm += __shfl_xor(sm, 8);
        if (n16 == 0) l_sh[w*16 + quad*4 + r] = sm;
    }
    __syncthreads();   // l_sh ready; Ps dead -> Osc may reuse its space

    // ---- epilogue: per-wave LDS transpose -> float4 out = g*O/l + x
    {
        const float g = gamma[0];
        float linv[4];
        #pragma unroll
        for (int qb = 0; qb < 4; ++qb) linv[qb] = 1.0f / l_sh[qb*16 + n16];
        float* Ow = Osc + w * 320;   // 16x20

        #pragma unroll
        for (int ct = 0; ct < 4; ++ct) {
            #pragma unroll
            for (int qb = 0; qb < 4; ++qb) {
                #pragma unroll
                for (int r = 0; r < 4; ++r)
                    Ow[(quad*4 + r) * 20 + n16] = O[ct][qb][r] * linv[qb];
                __builtin_amdgcn_wave_barrier();
                float4 ov = *(const float4*)&Ow[n16 * 20 + quad*4];
                __builtin_amdgcn_wave_barrier();
                const int c = half*256 + w*64 + ct*16 + n16;
                const int i = i0b + qb*16 + quad*4;
                const size_t off = ((size_t)b * 512 + c) * 2048 + i;
                float4 xv = *(const float4*)(x + off);
                float4 o;
                o.x = fmaf(g, ov.x, xv.x);
                o.y = fmaf(g, ov.y, xv.y);
                o.z = fmaf(g, ov.z, xv.z);
                o.w = fmaf(g, ov.w, xv.w);
                *(float4*)(out + off) = o;
            }
        }
    }
}

extern "C" void kernel_launch(void* const* d_in, const int* in_sizes, int n_in,
                              void* d_out, int out_size, void* d_ws, size_t ws_size,
                              hipStream_t stream)
{
    const float* x     = (const float*)d_in[0];
    const float* Wq    = (const float*)d_in[1];
    const float* bq    = (const float*)d_in[2];
    const float* Wk    = (const float*)d_in[3];
    const float* bk    = (const float*)d_in[4];
    const float* Wv    = (const float*)d_in[5];
    const float* bv    = (const float*)d_in[6];
    const float* gamma = (const float*)d_in[7];
    float* out = (float*)d_out;

    unsigned short* ws = (unsigned short*)d_ws;
    unsigned short* xt = ws;
    unsigned short* v  = xt + (size_t)B_ * L_ * C_;
    unsigned short* qt = v  + (size_t)B_ * C_ * L_;
    unsigned short* kt = qt + (size_t)B_ * L_ * 64;
    unsigned short* Wb = kt + (size_t)B_ * L_ * 64;

    dim3 gxw(L_ / 64, C_ / 64, B_ + 1);   // z=16 slice handles W cast
    cast_xw_kernel<<<gxw, 256, 0, stream>>>(x, xt, Wq, Wk, Wv, Wb);
    proj_mfma_kernel<<<1280, 256, 0, stream>>>(xt, Wb, bq, bk, bv, qt, kt, v);
    dim3 ga(64, 16);
    attn_kernel<<<ga, 256, 0, stream>>>(qt, kt, v, x, gamma, out);
}

// Round 13
// 299.826 us; speedup vs baseline: 1.4098x; 1.4098x over previous
//
#include <hip/hip_runtime.h>
#include <math.h>

static constexpr int B_  = 16;
static constexpr int C_  = 512;
static constexpr int L_  = 2048;

typedef __attribute__((ext_vector_type(8))) short bf16x8;
typedef __attribute__((ext_vector_type(4))) float f32x4;

__device__ __forceinline__ unsigned short f2bf(float f) {
    unsigned int u = __float_as_uint(f);
    unsigned int r = (u + 0x7FFFu + ((u >> 16) & 1u)) >> 16;   // RNE
    return (unsigned short)r;
}

// async global->LDS, 16 bytes per lane; LDS dest = uniform base + lane*16
__device__ __forceinline__ void async_copy16(const void* g, void* l) {
    __builtin_amdgcn_global_load_lds(
        (const __attribute__((address_space(1))) unsigned int*)g,
        (__attribute__((address_space(3))) unsigned int*)l, 16, 0, 0);
}

// ---------------------------------------------------------------------------
// MERGED cast kernel: grid (32, 8, 17).  z<16: x->xt transpose+cast;
// z==16: W cast (160 of 256 blocks).  (R11, verified)
// ---------------------------------------------------------------------------
__global__ __launch_bounds__(256)
void cast_xw_kernel(const float* __restrict__ x, unsigned short* __restrict__ xt,
                    const float* __restrict__ Wq, const float* __restrict__ Wk,
                    const float* __restrict__ Wv, unsigned short* __restrict__ Wb)
{
    const int t = threadIdx.x;
    if (blockIdx.z == 16) {
        const int bid = blockIdx.y * 32 + blockIdx.x;
        if (bid >= 160) return;
        const int idx = (bid * 256 + t) * 8;
        const int m = idx >> 9;
        const int c = idx & 511;
        const float* src = (m < 64) ? (Wq + (size_t)m * 512)
                         : (m < 128) ? (Wk + (size_t)(m - 64) * 512)
                                     : (Wv + (size_t)(m - 128) * 512);
        float4 a = *(const float4*)(src + c);
        float4 d = *(const float4*)(src + c + 4);
        union { unsigned short h[8]; uint4 v; } o;
        o.h[0]=f2bf(a.x); o.h[1]=f2bf(a.y); o.h[2]=f2bf(a.z); o.h[3]=f2bf(a.w);
        o.h[4]=f2bf(d.x); o.h[5]=f2bf(d.y); o.h[6]=f2bf(d.z); o.h[7]=f2bf(d.w);
        *(uint4*)(Wb + idx) = o.v;
        return;
    }

    __shared__ float T[64][65];
    const int l0 = blockIdx.x * 64;
    const int c0 = blockIdx.y * 64;
    const int b  = blockIdx.z;

    {
        const int cr = t >> 2;
        const int lq = (t & 3) * 4;
        const float* src = x + ((size_t)b * 512 + c0 + cr) * 2048 + l0 + lq;
        #pragma unroll
        for (int e = 0; e < 4; ++e) {
            float4 f = *(const float4*)(src + e * 16);
            const int lc = lq + e * 16;
            T[lc + 0][cr] = f.x;
            T[lc + 1][cr] = f.y;
            T[lc + 2][cr] = f.z;
            T[lc + 3][cr] = f.w;
        }
    }
    __syncthreads();
    {
        const int lr = t >> 2;
        const int cq = (t & 3) * 8;
        unsigned short* dst = xt + ((size_t)b * 2048 + l0 + lr) * 512 + c0;
        #pragma unroll
        for (int e = 0; e < 2; ++e) {
            union { unsigned short h[8]; uint4 v; } o;
            #pragma unroll
            for (int j = 0; j < 8; ++j) o.h[j] = f2bf(T[lr][cq + e*32 + j]);
            *(uint4*)(dst + cq + e*32) = o.v;
        }
    }
}

// ---------------------------------------------------------------------------
// Proj GEMM (MFMA, global_load_lds staging) — verified ~45us (R9 duplicate-
// launch measurement). XCD-chunked 1-D grid decode.
// ---------------------------------------------------------------------------
__global__ __launch_bounds__(256)
void proj_mfma_kernel(const unsigned short* __restrict__ xt,
                      const unsigned short* __restrict__ Wb,
                      const float* __restrict__ bq, const float* __restrict__ bk,
                      const float* __restrict__ bv,
                      unsigned short* __restrict__ qt, unsigned short* __restrict__ kt,
                      unsigned short* __restrict__ v)
{
    __shared__ unsigned short As[128 * 64];
    __shared__ unsigned short Bs[128 * 64];

    const int t     = threadIdx.x;
    const int bid   = blockIdx.x;
    const int xcd   = bid & 7;
    const int ii    = bid >> 3;
    const int nt5   = ii % 5;
    const int mloc  = ii / 5;
    const int mtile = xcd * 32 + mloc;
    const int row0  = mtile * 128;
    const int b     = mtile >> 4;
    const int l0    = (mtile & 15) * 128;
    const int c0t   = nt5 * 128;

    const int w    = t >> 6;
    const int lane = t & 63;
    const int quad = lane >> 4;
    const int n16  = lane & 15;
    const int mq   = (w & 1) * 64;
    const int nq   = (w >> 1) * 64;
    const int sr   = lane >> 3;
    const int sc   = (lane & 7) * 8;

    f32x4 acc[4][4];
    #pragma unroll
    for (int i = 0; i < 4; ++i)
        #pragma unroll
        for (int j = 0; j < 4; ++j) acc[i][j] = (f32x4){0.f,0.f,0.f,0.f};

    for (int kt_ = 0; kt_ < 512; kt_ += 64) {
        #pragma unroll
        for (int p = 0; p < 4; ++p) {
            const int rbase = w * 32 + p * 8;
            async_copy16(xt + ((size_t)(row0 + rbase + sr)) * 512 + kt_ + sc,
                         &As[rbase * 64]);
            async_copy16(Wb + ((size_t)(c0t + rbase + sr)) * 512 + kt_ + sc,
                         &Bs[rbase * 64]);
        }
        __syncthreads();

        #pragma unroll
        for (int ks = 0; ks < 2; ++ks) {
            bf16x8 a[4], bb[4];
            #pragma unroll
            for (int mt = 0; mt < 4; ++mt)
                a[mt] = *(const bf16x8*)&As[(mq + mt*16 + n16) * 64 + ks*32 + quad*8];
            #pragma unroll
            for (int nt = 0; nt < 4; ++nt)
                bb[nt] = *(const bf16x8*)&Bs[(nq + nt*16 + n16) * 64 + ks*32 + quad*8];
            #pragma unroll
            for (int mt = 0; mt < 4; ++mt)
                #pragma unroll
                for (int nt = 0; nt < 4; ++nt)
                    acc[mt][nt] = __builtin_amdgcn_mfma_f32_16x16x32_bf16(a[mt], bb[nt], acc[mt][nt], 0, 0, 0);
        }
        __syncthreads();
    }

    #pragma unroll
    for (int nt = 0; nt < 4; ++nt) {
        const int crow = c0t + nq + nt*16 + n16;
        const float bias = (crow < 64) ? bq[crow] : (crow < 128) ? bk[crow - 64] : bv[crow - 128];
        #pragma unroll
        for (int mt = 0; mt < 4; ++mt) {
            const int lb = l0 + mq + mt*16 + quad*4;
            if (crow < 64) {
                #pragma unroll
                for (int r = 0; r < 4; ++r)
                    qt[((size_t)b * 2048 + lb + r) * 64 + crow] = f2bf(acc[mt][nt][r] + bias);
            } else if (crow < 128) {
                #pragma unroll
                for (int r = 0; r < 4; ++r)
                    kt[((size_t)b * 2048 + lb + r) * 64 + crow - 64] = f2bf(acc[mt][nt][r] + bias);
            } else {
                ushort4 o;
                o.x = f2bf(acc[mt][nt][0] + bias);
                o.y = f2bf(acc[mt][nt][1] + bias);
                o.z = f2bf(acc[mt][nt][2] + bias);
                o.w = f2bf(acc[mt][nt][3] + bias);
                *(ushort4*)(v + ((size_t)b * 512 + crow - 128) * 2048 + lb) = o;
            }
        }
    }
}

// ---------------------------------------------------------------------------
// Attention: verified R2 kernel (148-151us, FETCH 55MB, conflicts 2.36M).
// grid (32,16), block 256 (4 waves). j-tile 32, 64 iters, 1 barrier/iter.
// V via global_load_lds double-buffered; K register-double-buffered;
// fixed-max softmax exp(s-80); Vs XOR-swizzle; XCD batch remap; setprio.
// Structural notes (measured, session R0-R12): O accumulator (128 AGPR) +
// 112 VGPR caps at 2 waves/SIMD — smaller-O variants duplicate QK/K traffic
// and measure 269us (R4/R12); pipe-level grafts (swizzle/XCD/setprio/vmcnt)
// move counters but not time. This is the optimum of the explored space.
// ---------------------------------------------------------------------------
__global__ __launch_bounds__(256, 2)
void attn_kernel(const unsigned short* __restrict__ qt,
                 const unsigned short* __restrict__ kt,
                 const unsigned short* __restrict__ vg,
                 const float* __restrict__ x,
                 const float* __restrict__ gamma,
                 float* __restrict__ out)
{
    // manual LDS layout: Vs 2x32KB | Ps 2x(64x40) shorts | l_sh ; Osc overlaps Ps
    __shared__ __align__(16) char smem[76032];
    unsigned short* Vs   = (unsigned short*)smem;            // [2][512*32]
    unsigned short* Ps   = (unsigned short*)(smem + 65536);  // [2][64*40]
    float*          l_sh = (float*)(smem + 75776);           // [64]
    float*          Osc  = (float*)(smem + 65536);           // epilogue only

    const int t    = threadIdx.x;
    const int nlin = blockIdx.y * 32 + blockIdx.x;
    const int k_   = nlin >> 3;
    const int b    = ((nlin & 7) << 1) | (k_ & 1);
    const int i0b  = (k_ >> 1) * 64;
    const int w    = t >> 6;
    const int lane = t & 63;
    const int quad = lane >> 4;
    const int n16  = lane & 15;

    bf16x8 Qf[2];
    {
        const unsigned short* qp = qt + ((size_t)b * 2048 + i0b + w*16 + n16) * 64 + quad * 8;
        Qf[0] = *(const bf16x8*)(qp);
        Qf[1] = *(const bf16x8*)(qp + 32);
    }

    const unsigned short* kbase = kt + (size_t)b * 2048 * 64;
    const unsigned short* vbase = vg + (size_t)b * 512 * 2048;

    const int vrow_in  = lane >> 2;
    const int vcol_sw  = ((lane & 3) ^ ((lane >> 3) & 3)) * 8;
    const int vread_sw = (quad ^ ((n16 >> 1) & 3)) * 8;

    bf16x8 Kc[2][2], Kn[2][2];
    #pragma unroll
    for (int jb = 0; jb < 2; ++jb)
        #pragma unroll
        for (int h = 0; h < 2; ++h)
            Kc[jb][h] = *(const bf16x8*)(kbase + (size_t)(jb*16 + n16) * 64 + h*32 + quad*8);

    #pragma unroll
    for (int p = 0; p < 8; ++p) {
        const int row = w*128 + p*16 + vrow_in;
        async_copy16(vbase + (size_t)row * 2048 + vcol_sw,
                     Vs + (size_t)(w*128 + p*16) * 32 + (lane * 8));
    }

    float l_part[4] = {0.f, 0.f, 0.f, 0.f};
    f32x4 O[8][4];
    #pragma unroll
    for (int ct = 0; ct < 8; ++ct)
        #pragma unroll
        for (int qb = 0; qb < 4; ++qb) O[ct][qb] = (f32x4){0.f,0.f,0.f,0.f};

    __syncthreads();   // Vs[0] ready

    for (int it = 0; it < 64; ++it) {
        const int j0 = it * 32;
        const int cb = it & 1;
        const int nb = cb ^ 1;
        const int j0n = (j0 + 32) & 2047;

        f32x4 s[2];
        __builtin_amdgcn_s_setprio(1);
        #pragma unroll
        for (int jb = 0; jb < 2; ++jb) {
            s[jb] = (f32x4){0.f,0.f,0.f,0.f};
            s[jb] = __builtin_amdgcn_mfma_f32_16x16x32_bf16(Qf[0], Kc[jb][0], s[jb], 0, 0, 0);
            s[jb] = __builtin_amdgcn_mfma_f32_16x16x32_bf16(Qf[1], Kc[jb][1], s[jb], 0, 0, 0);
        }
        __builtin_amdgcn_s_setprio(0);

        #pragma unroll
        for (int jb = 0; jb < 2; ++jb) {
            #pragma unroll
            for (int r = 0; r < 4; ++r) {
                const float pv = __expf(s[jb][r] - 80.0f);
                l_part[r] += pv;
                Ps[(size_t)cb * (64*40) + (w*16 + quad*4 + r) * 40 + jb*16 + n16] = f2bf(pv);
            }
        }

        __syncthreads();   // Ps[cb] visible; Vs[cb] DMA (issued last iter) drained

        #pragma unroll
        for (int p = 0; p < 8; ++p) {
            const int row = w*128 + p*16 + vrow_in;
            async_copy16(vbase + (size_t)row * 2048 + j0n + vcol_sw,
                         Vs + (size_t)nb * (512*32) + (size_t)(w*128 + p*16) * 32 + (lane * 8));
        }
        #pragma unroll
        for (int jb = 0; jb < 2; ++jb)
            #pragma unroll
            for (int h = 0; h < 2; ++h)
                Kn[jb][h] = *(const bf16x8*)(kbase + (size_t)(j0n + jb*16 + n16) * 64 + h*32 + quad*8);

        {
            bf16x8 Pf[4];
            #pragma unroll
            for (int qb = 0; qb < 4; ++qb)
                Pf[qb] = *(const bf16x8*)&Ps[(size_t)cb * (64*40) + (qb*16 + n16) * 40 + quad*8];
            __builtin_amdgcn_s_setprio(1);
            #pragma unroll
            for (int ct = 0; ct < 8; ++ct) {
                bf16x8 Vf = *(const bf16x8*)&Vs[(size_t)cb * (512*32) + (size_t)(w*128 + ct*16 + n16) * 32 + vread_sw];
                #pragma unroll
                for (int qb = 0; qb < 4; ++qb)
                    O[ct][qb] = __builtin_amdgcn_mfma_f32_16x16x32_bf16(Vf, Pf[qb], O[ct][qb], 0, 0, 0);
            }
            __builtin_amdgcn_s_setprio(0);
        }

        #pragma unroll
        for (int jb = 0; jb < 2; ++jb)
            #pragma unroll
            for (int h = 0; h < 2; ++h)
                Kc[jb][h] = Kn[jb][h];
    }

    #pragma unroll
    for (int r = 0; r < 4; ++r) {
        float sm = l_part[r];
        sm += __shfl_xor(sm, 1);
        sm += __shfl_xor(sm, 2);
        sm += __shfl_xor(sm, 4);
        sm += __shfl_xor(sm, 8);
        if (n16 == 0) l_sh[w*16 + quad*4 + r] = sm;
    }
    __syncthreads();

    {
        const float g = gamma[0];
        float linv[4];
        #pragma unroll
        for (int qb = 0; qb < 4; ++qb) linv[qb] = 1.0f / l_sh[qb*16 + n16];
        float* Ow = Osc + w * 320;   // 16x20

        #pragma unroll
        for (int ct = 0; ct < 8; ++ct) {
            #pragma unroll
            for (int qb = 0; qb < 4; ++qb) {
                #pragma unroll
                for (int r = 0; r < 4; ++r)
                    Ow[(quad*4 + r) * 20 + n16] = O[ct][qb][r] * linv[qb];
                __builtin_amdgcn_wave_barrier();
                float4 ov = *(const float4*)&Ow[n16 * 20 + quad*4];
                __builtin_amdgcn_wave_barrier();
                const int c = w*128 + ct*16 + n16;
                const int i = i0b + qb*16 + quad*4;
                const size_t off = ((size_t)b * 512 + c) * 2048 + i;
                float4 xv = *(const float4*)(x + off);
                float4 o;
                o.x = fmaf(g, ov.x, xv.x);
                o.y = fmaf(g, ov.y, xv.y);
                o.z = fmaf(g, ov.z, xv.z);
                o.w = fmaf(g, ov.w, xv.w);
                *(float4*)(out + off) = o;
            }
        }
    }
}

extern "C" void kernel_launch(void* const* d_in, const int* in_sizes, int n_in,
                              void* d_out, int out_size, void* d_ws, size_t ws_size,
                              hipStream_t stream)
{
    const float* x     = (const float*)d_in[0];
    const float* Wq    = (const float*)d_in[1];
    const float* bq    = (const float*)d_in[2];
    const float* Wk    = (const float*)d_in[3];
    const float* bk    = (const float*)d_in[4];
    const float* Wv    = (const float*)d_in[5];
    const float* bv    = (const float*)d_in[6];
    const float* gamma = (const float*)d_in[7];
    float* out = (float*)d_out;

    unsigned short* ws = (unsigned short*)d_ws;
    unsigned short* xt = ws;
    unsigned short* v  = xt + (size_t)B_ * L_ * C_;
    unsigned short* qt = v  + (size_t)B_ * C_ * L_;
    unsigned short* kt = qt + (size_t)B_ * L_ * 64;
    unsigned short* Wb = kt + (size_t)B_ * L_ * 64;

    dim3 gxw(L_ / 64, C_ / 64, B_ + 1);   // z=16 slice handles W cast
    cast_xw_kernel<<<gxw, 256, 0, stream>>>(x, xt, Wq, Wk, Wv, Wb);
    proj_mfma_kernel<<<1280, 256, 0, stream>>>(xt, Wb, bq, bk, bv, qt, kt, v);
    dim3 ga(L_ / 64, B_);
    attn_kernel<<<ga, 256, 0, stream>>>(qt, kt, v, x, gamma, out);
}